// Round 5
// baseline (75.320 us; speedup 1.0000x reference)
//
#include <hip/hip_runtime.h>

typedef __attribute__((ext_vector_type(8))) short          short8_t;   // 8 bf16
typedef __attribute__((ext_vector_type(8))) unsigned short ushort8_t;
typedef __attribute__((ext_vector_type(4))) float          floatx4;

constexpr int N_ROWS = 8192;
constexpr int DIM    = 64;
constexpr int PANEL  = 128 * DIM;   // 8192 ushorts = 16 KiB per (panel, hi/lo)

// f32 -> bf16 round-to-nearest-even
__device__ __forceinline__ unsigned short bf16_rne(float f) {
    unsigned int u = __float_as_uint(f);
    u += 0x7FFFu + ((u >> 16) & 1u);
    return (unsigned short)(u >> 16);
}

// ---------------------------------------------------------------------------
// Kernel 1: norms + hi/lo bf16 split, written in FRAGMENT order:
//   group g of panel p, k = ks*32 + lg*8 + e:
//   ushort offset in panel-half = ((g*2 + ks)*64 + lg*16 + li)*8 + e
// so a per-(group,ks) fragment load is one contiguous 1-KiB wave load.
// ---------------------------------------------------------------------------
__global__ void __launch_bounds__(256)
split_norms_kernel(const float* __restrict__ X, const float* __restrict__ Y,
                   float* __restrict__ x2, float* __restrict__ y2,
                   unsigned short* __restrict__ Xs, unsigned short* __restrict__ Ys) {
    const int t  = blockIdx.x * 256 + threadIdx.x;   // [0, 16384)
    const int r  = t >> 1;                           // row
    const int h  = t & 1;                            // k-half (== ks)
    const int p  = r >> 7;
    const int rl = r & 127;
    const int g  = rl >> 4;
    const int li = rl & 15;
    const size_t pb = (size_t)p * (2 * PANEL);

    const float4* xr = reinterpret_cast<const float4*>(X + (size_t)r * DIM + h * 32);
    const float4* yr = reinterpret_cast<const float4*>(Y + (size_t)r * DIM + h * 32);

    float sx = 0.f, sy = 0.f;
#pragma unroll
    for (int c = 0; c < 4; ++c) {                    // lg = c
        const int off = ((g * 2 + h) * 64 + c * 16 + li) * 8;
        float f[8];
        ushort8_t hi, lo;

        *reinterpret_cast<float4*>(&f[0]) = xr[2 * c];
        *reinterpret_cast<float4*>(&f[4]) = xr[2 * c + 1];
#pragma unroll
        for (int e = 0; e < 8; ++e) {
            sx = fmaf(f[e], f[e], sx);
            unsigned short hh = bf16_rne(f[e]);
            hi[e] = hh;
            lo[e] = bf16_rne(f[e] - __uint_as_float((unsigned int)hh << 16));
        }
        *reinterpret_cast<ushort8_t*>(&Xs[pb + off])         = hi;
        *reinterpret_cast<ushort8_t*>(&Xs[pb + PANEL + off]) = lo;

        *reinterpret_cast<float4*>(&f[0]) = yr[2 * c];
        *reinterpret_cast<float4*>(&f[4]) = yr[2 * c + 1];
#pragma unroll
        for (int e = 0; e < 8; ++e) {
            sy = fmaf(f[e], f[e], sy);
            unsigned short hh = bf16_rne(f[e]);
            hi[e] = hh;
            lo[e] = bf16_rne(f[e] - __uint_as_float((unsigned int)hh << 16));
        }
        *reinterpret_cast<ushort8_t*>(&Ys[pb + off])         = hi;
        *reinterpret_cast<ushort8_t*>(&Ys[pb + PANEL + off]) = lo;
    }
    sx += __shfl_xor(sx, 1);
    sy += __shfl_xor(sy, 1);
    if (h == 0) { x2[r] = sx; y2[r] = sy; }
}

// ---------------------------------------------------------------------------
// Kernel 2: row-band sweep for sequential stores.
// Block (256 thr, 4 waves) = 256-row band x 1024 cols. Wave w owns 64 rows
// (4 X-groups, A-frags preloaded in regs) and sweeps 16 chunks of 64 cols.
// Per chunk: 16 B-frag L2 loads, 96 MFMA (split bf16), repack via wave-
// private swizzled LDS (16 KiB/wave), exp, then 16 stores each covering
// 4 rows x 256 B contiguous. Chunks advance so every row receives 16
// sequential 256-B writes. No barriers.
// ---------------------------------------------------------------------------
__global__ void __launch_bounds__(256, 2)
rbf_mfma_kernel(const unsigned short* __restrict__ Xs,
                const unsigned short* __restrict__ Ys,
                const float* __restrict__ x2, const float* __restrict__ y2,
                float* __restrict__ out) {
    __shared__ float4 Rbuf[4][1024];   // 64 KiB; wave-private 16 KiB slices

    const int tid  = threadIdx.x;
    const int lane = tid & 63;
    const int w    = tid >> 6;
    const int li   = lane & 15;
    const int lg   = lane >> 4;

    const int band = blockIdx.x & 31;          // 32 row bands of 256
    const int cq   = blockIdx.x >> 5;          // 8 col groups of 1024
    const int row0 = band * 256 + w * 64;      // this wave's first row
    const int colbase = cq * 1024;

    // ---- preload A fragments (4 groups x 2 ks x hi/lo) : 64 VGPRs ----
    short8_t aH[4][2], aL[4][2];
    const int gx0 = row0 >> 4;
#pragma unroll
    for (int gx = 0; gx < 4; ++gx) {
        const int gabs = gx0 + gx;
        const unsigned short* base = Xs + (size_t)(gabs >> 3) * (2 * PANEL);
        const int g = gabs & 7;
#pragma unroll
        for (int ks = 0; ks < 2; ++ks) {
            const int off = ((g * 2 + ks) * 64 + lane) * 8;
            aH[gx][ks] = *reinterpret_cast<const short8_t*>(base + off);
            aL[gx][ks] = *reinterpret_cast<const short8_t*>(base + PANEL + off);
        }
    }

    for (int ch = 0; ch < 16; ++ch) {
        const int c0 = colbase + ch * 64;

        // ---- B fragments for 4 Y-groups (direct from L2) ----
        short8_t bH[4][2], bL[4][2];
        const int gy0 = c0 >> 4;
#pragma unroll
        for (int gy = 0; gy < 4; ++gy) {
            const int gabs = gy0 + gy;
            const unsigned short* base = Ys + (size_t)(gabs >> 3) * (2 * PANEL);
            const int g = gabs & 7;
#pragma unroll
            for (int ks = 0; ks < 2; ++ks) {
                const int off = ((g * 2 + ks) * 64 + lane) * 8;
                bH[gy][ks] = *reinterpret_cast<const short8_t*>(base + off);
                bL[gy][ks] = *reinterpret_cast<const short8_t*>(base + PANEL + off);
            }
        }

        // ---- 96 MFMA: Xh.Yh + Xh.Yl + Xl.Yh (operands swapped: lane li = row)
        floatx4 acc[4][4] = {};
#pragma unroll
        for (int ks = 0; ks < 2; ++ks)
#pragma unroll
            for (int gy = 0; gy < 4; ++gy)
#pragma unroll
                for (int gx = 0; gx < 4; ++gx) {
                    acc[gx][gy] = __builtin_amdgcn_mfma_f32_16x16x32_bf16(
                        bH[gy][ks], aH[gx][ks], acc[gx][gy], 0, 0, 0);
                    acc[gx][gy] = __builtin_amdgcn_mfma_f32_16x16x32_bf16(
                        bL[gy][ks], aH[gx][ks], acc[gx][gy], 0, 0, 0);
                    acc[gx][gy] = __builtin_amdgcn_mfma_f32_16x16x32_bf16(
                        bH[gy][ks], aL[gx][ks], acc[gx][gy], 0, 0, 0);
                }

        // ---- repack: acc(row=gx*16+li, colgran=gy*4+lg) -> swizzled LDS ----
        // granule index = row*16 + (cg ^ (row&7)): conflict-free per 8-lane group
#pragma unroll
        for (int gx = 0; gx < 4; ++gx) {
            const int row = gx * 16 + li;
#pragma unroll
            for (int gy = 0; gy < 4; ++gy) {
                const int cg = gy * 4 + lg;
                Rbuf[w][row * 16 + (cg ^ (row & 7))] =
                    make_float4(acc[gx][gy][0], acc[gx][gy][1],
                                acc[gx][gy][2], acc[gx][gy][3]);
            }
        }
        __builtin_amdgcn_s_waitcnt(0);   // lgkmcnt(0): wave-private RAW

        // ---- read back row-major, exp, store 4 rows x 256 B per instr ----
        const float4 yv = *reinterpret_cast<const float4*>(&y2[c0 + li * 4]);
#pragma unroll
        for (int i = 0; i < 16; ++i) {
            const int rr = i * 4 + lg;                 // local row 0..63
            const float4 v = Rbuf[w][rr * 16 + (li ^ (rr & 7))];
            const int grow = row0 + rr;
            const float xs = x2[grow];
            float4 o;
            o.x = __expf(-fmaxf(fmaf(-2.f, v.x, xs + yv.x), 0.f));
            o.y = __expf(-fmaxf(fmaf(-2.f, v.y, xs + yv.y), 0.f));
            o.z = __expf(-fmaxf(fmaf(-2.f, v.z, xs + yv.z), 0.f));
            o.w = __expf(-fmaxf(fmaf(-2.f, v.w, xs + yv.w), 0.f));
            *reinterpret_cast<float4*>(out + (size_t)grow * N_ROWS + c0 + li * 4) = o;
        }
    }
}

// ---------------------------------------------------------------------------
extern "C" void kernel_launch(void* const* d_in, const int* in_sizes, int n_in,
                              void* d_out, int out_size, void* d_ws, size_t ws_size,
                              hipStream_t stream) {
    const float* X = (const float*)d_in[0];
    const float* Y = (const float*)d_in[1];
    float* out = (float*)d_out;

    float* x2 = (float*)d_ws;                              // 8192 f32
    float* y2 = x2 + N_ROWS;                               // 8192 f32
    unsigned short* Xs = (unsigned short*)(y2 + N_ROWS);   // 2 MiB
    unsigned short* Ys = Xs + (N_ROWS / 128) * 2 * PANEL;  // 2 MiB

    split_norms_kernel<<<(2 * N_ROWS) / 256, 256, 0, stream>>>(X, Y, x2, y2, Xs, Ys);

    rbf_mfma_kernel<<<256, 256, 0, stream>>>(Xs, Ys, x2, y2, out);
}

// Round 7
// 73.412 us; speedup vs baseline: 1.0260x; 1.0260x over previous
//
#include <hip/hip_runtime.h>

typedef __attribute__((ext_vector_type(8))) short          short8_t;   // 8 bf16
typedef __attribute__((ext_vector_type(8))) unsigned short ushort8_t;
typedef __attribute__((ext_vector_type(4))) float          floatx4;

constexpr int N_ROWS = 8192;
constexpr int DIM    = 64;
constexpr int PANEL  = 128 * DIM;   // 8192 ushorts = 16 KiB per (panel, hi/lo)

// f32 -> bf16 round-to-nearest-even
__device__ __forceinline__ unsigned short bf16_rne(float f) {
    unsigned int u = __float_as_uint(f);
    u += 0x7FFFu + ((u >> 16) & 1u);
    return (unsigned short)(u >> 16);
}

// ---------------------------------------------------------------------------
// Kernel 1: NEGATED norms + hi/lo bf16 split, written in FRAGMENT order:
//   group g of panel p, k = ks*32 + lg*8 + e:
//   ushort offset in panel-half = ((g*2 + ks)*64 + lg*16 + li)*8 + e
// so a per-(group,ks) fragment load is one contiguous 1-KiB wave load.
// ---------------------------------------------------------------------------
__global__ void __launch_bounds__(256)
split_norms_kernel(const float* __restrict__ X, const float* __restrict__ Y,
                   float* __restrict__ x2n, float* __restrict__ y2n,
                   unsigned short* __restrict__ Xs, unsigned short* __restrict__ Ys) {
    const int t  = blockIdx.x * 256 + threadIdx.x;   // [0, 16384)
    const int r  = t >> 1;                           // row
    const int h  = t & 1;                            // k-half (== ks)
    const int p  = r >> 7;
    const int rl = r & 127;
    const int g  = rl >> 4;
    const int li = rl & 15;
    const size_t pb = (size_t)p * (2 * PANEL);

    const float4* xr = reinterpret_cast<const float4*>(X + (size_t)r * DIM + h * 32);
    const float4* yr = reinterpret_cast<const float4*>(Y + (size_t)r * DIM + h * 32);

    float sx = 0.f, sy = 0.f;
#pragma unroll
    for (int c = 0; c < 4; ++c) {                    // lg = c
        const int off = ((g * 2 + h) * 64 + c * 16 + li) * 8;
        float f[8];
        ushort8_t hi, lo;

        *reinterpret_cast<float4*>(&f[0]) = xr[2 * c];
        *reinterpret_cast<float4*>(&f[4]) = xr[2 * c + 1];
#pragma unroll
        for (int e = 0; e < 8; ++e) {
            sx = fmaf(f[e], f[e], sx);
            unsigned short hh = bf16_rne(f[e]);
            hi[e] = hh;
            lo[e] = bf16_rne(f[e] - __uint_as_float((unsigned int)hh << 16));
        }
        *reinterpret_cast<ushort8_t*>(&Xs[pb + off])         = hi;
        *reinterpret_cast<ushort8_t*>(&Xs[pb + PANEL + off]) = lo;

        *reinterpret_cast<float4*>(&f[0]) = yr[2 * c];
        *reinterpret_cast<float4*>(&f[4]) = yr[2 * c + 1];
#pragma unroll
        for (int e = 0; e < 8; ++e) {
            sy = fmaf(f[e], f[e], sy);
            unsigned short hh = bf16_rne(f[e]);
            hi[e] = hh;
            lo[e] = bf16_rne(f[e] - __uint_as_float((unsigned int)hh << 16));
        }
        *reinterpret_cast<ushort8_t*>(&Ys[pb + off])         = hi;
        *reinterpret_cast<ushort8_t*>(&Ys[pb + PANEL + off]) = lo;
    }
    sx += __shfl_xor(sx, 1);
    sy += __shfl_xor(sy, 1);
    if (h == 0) { x2n[r] = -sx; y2n[r] = -sy; }      // negated norms
}

// ---------------------------------------------------------------------------
// Kernel 2: one wave per 64x64 output tile. NO LDS, NO barrier.
// Fragments loaded straight from the fragment-ordered panels (L2-resident,
// 1 KiB contiguous per wave per load). 96 MFMA (Xh.Yh + Xh.Yl + Xl.Yh),
// operands swapped so each lane's 4 acc regs = 4 consecutive output columns.
// Output: exp(min(2*xy - x2 - y2, 0)) via NON-TEMPORAL float4 stores
// (write-once data; bypass L2/L3 write-allocate).
// ---------------------------------------------------------------------------
__global__ void __launch_bounds__(64)
rbf_mfma_kernel(const unsigned short* __restrict__ Xs,
                const unsigned short* __restrict__ Ys,
                const float* __restrict__ x2n, const float* __restrict__ y2n,
                float* __restrict__ out) {
    const int lane = threadIdx.x;
    const int row0 = blockIdx.y * 64;
    const int col0 = blockIdx.x * 64;
    const unsigned short* Xp = Xs + (size_t)(blockIdx.y >> 1) * (2 * PANEL);
    const unsigned short* Yp = Ys + (size_t)(blockIdx.x >> 1) * (2 * PANEL);
    const int gx0 = (blockIdx.y & 1) * 4;   // A row-groups gx0..gx0+3
    const int gy0 = (blockIdx.x & 1) * 4;   // B col-groups gy0..gy0+3

    floatx4 acc[4][4] = {};

#define GF(P, hl, g, ks)                                                       \
    (*reinterpret_cast<const short8_t*>(                                       \
        (P) + (hl) * PANEL + (((g) * 2 + (ks)) * 64 + lane) * 8))

#pragma unroll
    for (int ks = 0; ks < 2; ++ks) {
        short8_t aH[4], bH[4], aL[4], bL[4];
#pragma unroll
        for (int mi = 0; mi < 4; ++mi) aH[mi] = GF(Xp, 0, gx0 + mi, ks);
#pragma unroll
        for (int ni = 0; ni < 4; ++ni) bH[ni] = GF(Yp, 0, gy0 + ni, ks);
#pragma unroll
        for (int mi = 0; mi < 4; ++mi)
#pragma unroll
            for (int ni = 0; ni < 4; ++ni)
                acc[mi][ni] = __builtin_amdgcn_mfma_f32_16x16x32_bf16(
                    bH[ni], aH[mi], acc[mi][ni], 0, 0, 0);   // Xh . Yh
#pragma unroll
        for (int ni = 0; ni < 4; ++ni) bL[ni] = GF(Yp, 1, gy0 + ni, ks);
#pragma unroll
        for (int mi = 0; mi < 4; ++mi)
#pragma unroll
            for (int ni = 0; ni < 4; ++ni)
                acc[mi][ni] = __builtin_amdgcn_mfma_f32_16x16x32_bf16(
                    bL[ni], aH[mi], acc[mi][ni], 0, 0, 0);   // Xh . Yl
#pragma unroll
        for (int mi = 0; mi < 4; ++mi) aL[mi] = GF(Xp, 1, gx0 + mi, ks);
#pragma unroll
        for (int mi = 0; mi < 4; ++mi)
#pragma unroll
            for (int ni = 0; ni < 4; ++ni)
                acc[mi][ni] = __builtin_amdgcn_mfma_f32_16x16x32_bf16(
                    bH[ni], aL[mi], acc[mi][ni], 0, 0, 0);   // Xl . Yh
    }
#undef GF

    // ---- epilogue: lane (li,lg) reg j -> out[row0+mi*16+li][col0+ni*16+lg*4+j]
    // out = exp(min(2*xy + (-x2) + (-y2), 0)); non-temporal full-line stores.
    const int li = lane & 15;
    const int lg = lane >> 4;
    const int orow = row0 + li;
    const int ocol = col0 + lg * 4;
#pragma unroll
    for (int mi = 0; mi < 4; ++mi) {
        const float xs = x2n[orow + mi * 16];
        float* obase = out + (size_t)(orow + mi * 16) * N_ROWS + ocol;
#pragma unroll
        for (int ni = 0; ni < 4; ++ni) {
            const float4 yv = *reinterpret_cast<const float4*>(&y2n[ocol + ni * 16]);
            floatx4 o;
            o[0] = __expf(fminf(fmaf(2.f, acc[mi][ni][0], xs + yv.x), 0.f));
            o[1] = __expf(fminf(fmaf(2.f, acc[mi][ni][1], xs + yv.y), 0.f));
            o[2] = __expf(fminf(fmaf(2.f, acc[mi][ni][2], xs + yv.z), 0.f));
            o[3] = __expf(fminf(fmaf(2.f, acc[mi][ni][3], xs + yv.w), 0.f));
            __builtin_nontemporal_store(o, reinterpret_cast<floatx4*>(obase + ni * 16));
        }
    }
}

// ---------------------------------------------------------------------------
extern "C" void kernel_launch(void* const* d_in, const int* in_sizes, int n_in,
                              void* d_out, int out_size, void* d_ws, size_t ws_size,
                              hipStream_t stream) {
    const float* X = (const float*)d_in[0];
    const float* Y = (const float*)d_in[1];
    float* out = (float*)d_out;

    float* x2n = (float*)d_ws;                             // 8192 f32 (negated)
    float* y2n = x2n + N_ROWS;                             // 8192 f32 (negated)
    unsigned short* Xs = (unsigned short*)(y2n + N_ROWS);  // 2 MiB
    unsigned short* Ys = Xs + (N_ROWS / 128) * 2 * PANEL;  // 2 MiB

    split_norms_kernel<<<(2 * N_ROWS) / 256, 256, 0, stream>>>(X, Y, x2n, y2n, Xs, Ys);

    dim3 grid(N_ROWS / 64, N_ROWS / 64);   // 128 x 128 one-wave blocks
    rbf_mfma_kernel<<<grid, 64, 0, stream>>>(Xs, Ys, x2n, y2n, out);
}